// Round 9
// baseline (116.572 us; speedup 1.0000x reference)
//
#include <hip/hip_runtime.h>
#include <hip/hip_bf16.h>

// RelationNetwork fused pipeline, bf16 MFMA (gfx950).
//
// Factorizations:
//  (1) pair@W1 = u[i]+v[j]  -> one 4096x512x512 GEMM (K1).
//  (2) ctx-ctx pair sum is choice-invariant -> computed once per b inside K2.
//  (3) f_phi fused into K2 (agg rows live in LDS; no K3, no aggb round-trip).
//  (4) K1 stages fp32 X into a shared LDS bf16 A-tile.
//  (5) UV stored bf16 (halves UV write + K2 staging traffic).
//  (6) prep via LDS 64x64 tile transpose; K1 256 blocks x 512 thr.
//  (7) r9: K2 1024 thr / 16 waves (4 waves/SIMD, was 2) -- per-wave tile
//      3mt x 4nt (acc 48 VGPR), ctx sum split into two S slots (no race),
//      f_phi 1 tile/wave. Same math, same rounding points.
//
// ws layout (bytes):
//   [0,        524288)   Wp   bf16 [512][512]  Wp[j][k]=W1'[k][j]
//   [524288,   655360)   W2T  bf16 [256][256]
//   [655360,   786432)   W3T  bf16 [256][256]
//   [786432,   4980736)  UV   bf16 [4096][512] row b*16+p; cols 0..255=u, 256..511=v

typedef __bf16 bf16_t;
typedef bf16_t bf16x8 __attribute__((ext_vector_type(8)));
typedef bf16_t bf16x4 __attribute__((ext_vector_type(4)));
typedef float f32x4 __attribute__((ext_vector_type(4)));

#define MFMA16(a, b, c) __builtin_amdgcn_mfma_f32_16x16x32_bf16((a), (b), (c), 0, 0, 0)

// ---- K0: weight transposes via LDS tiles (96 blocks x 256 thr) -------------
__global__ __launch_bounds__(256) void prep_kernel(
    const float* __restrict__ W1, const float* __restrict__ W2,
    const float* __restrict__ W3, bf16_t* __restrict__ Wp,
    bf16_t* __restrict__ W2T, bf16_t* __restrict__ W3T) {
  __shared__ float Ts[64][65];
  const int b = blockIdx.x;
  const int t = threadIdx.x;
  const int r = t >> 6;          // 0..3
  const int c = t & 63;
  const float* srcP;
  bf16_t* dstP;
  int srcRow, srcCol, dr0, dc0, dstride;
  if (b < 64) {                  // Wp tile: tk = b>>3, tj = b&7
    const int k0 = (b >> 3) * 64, j0 = (b & 7) * 64;
    srcP = W1; dstP = Wp; dstride = 512;
    srcRow = (j0 < 256) ? k0 : 512 + k0;
    srcCol = (j0 < 256) ? j0 : j0 - 256;
    dr0 = j0; dc0 = k0;
  } else if (b < 80) {           // W2T tile
    const int s = b - 64;
    const int k0 = (s >> 2) * 64, n0 = (s & 3) * 64;
    srcP = W2; dstP = W2T; dstride = 256;
    srcRow = k0; srcCol = n0; dr0 = n0; dc0 = k0;
  } else {                       // W3T tile
    const int s = b - 80;
    const int k0 = (s >> 2) * 64, n0 = (s & 3) * 64;
    srcP = W3; dstP = W3T; dstride = 256;
    srcRow = k0; srcCol = n0; dr0 = n0; dc0 = k0;
  }
  for (int i = 0; i < 16; ++i) {           // 16 iters x 4 rows = 64 rows
    const int a = i * 4 + r;
    Ts[a][c] = srcP[(size_t)(srcRow + a) * 256 + srcCol + c];
  }
  __syncthreads();
  for (int i = 0; i < 16; ++i) {
    const int j = i * 4 + r;
    dstP[(size_t)(dr0 + j) * dstride + dc0 + c] = (bf16_t)Ts[c][j];
  }
}

// ---- K1: UV = X @ Wp^T  (M=4096, N=512, K=512), bf16 output ----------------
// 256 blocks = 64 Mtiles(64) x 4 Ntiles(128); 512 thr = 8 waves (4mt x 1nt).
__global__ __launch_bounds__(512) void k1_kernel(
    const float* __restrict__ ctx, const float* __restrict__ cho,
    const bf16_t* __restrict__ Wp, bf16_t* __restrict__ UV) {
  __shared__ bf16_t As[64][264];           // 33.8 KB; row bank-stride 4 -> 2-way max
  const int bm = blockIdx.x & 63;
  const int bn = blockIdx.x >> 6;          // 0..3
  const int t = threadIdx.x;
  const int lane = t & 63;
  const int w = t >> 6;                    // 0..7
  const int col = lane & 15;
  const int quad = lane >> 4;
  const int n = bn * 128 + w * 16 + col;
  const int sr = t >> 3;                   // staging: 8 threads/row
  const int gr = bm * 64 + sr;             // X row = b*16 + p
  const int bi = gr >> 4;
  const int p = gr & 15;
  const float* src = (p < 8) ? ctx + (size_t)(bi * 8 + p) * 512
                             : cho + (size_t)(bi * 8 + (p - 8)) * 512;
  const int cb = (t & 7) * 4;
  f32x4 acc[4] = {};
  for (int half = 0; half < 2; ++half) {
    const int kbase = half * 256;
    for (int i = 0; i < 8; ++i) {
      const int c = cb + i * 32;
      const f32x4 x = *(const f32x4*)(src + kbase + c);
      bf16x4 y;
      for (int e = 0; e < 4; ++e) y[e] = (bf16_t)x[e];
      *(bf16x4*)(&As[sr][c]) = y;
    }
    __syncthreads();
    for (int ks = 0; ks < 8; ++ks) {
      const int k = ks * 32 + quad * 8;
      bf16x8 af[4];
      for (int mt = 0; mt < 4; ++mt)
        af[mt] = *(const bf16x8*)(&As[mt * 16 + col][k]);
      const bf16x8 bf = *(const bf16x8*)(Wp + (size_t)n * 512 + kbase + k);
      for (int mt = 0; mt < 4; ++mt) acc[mt] = MFMA16(af[mt], bf, acc[mt]);
    }
    __syncthreads();
  }
  for (int mt = 0; mt < 4; ++mt)
    for (int reg = 0; reg < 4; ++reg) {
      const int r = bm * 64 + mt * 16 + quad * 4 + reg;
      UV[(size_t)r * 512 + n] = (bf16_t)acc[mt][reg];
    }
}

// ---- K2: merged relation stage + f_phi. One block per b (256 blk, 1024 thr).
// Rows r in [0,192): r<56 ctx pair; 56..63 zero pad; r=64+ch*16+rr choice pair.
// h1 staged in LDS in two K=128 phases (52 KB). 16 waves: g=w&3 -> 3 mt tiles
// (mt = 3g+{0,1,2}), q=w>>2 -> nt quarter. Epilogue (h1 dead, LDS overlay):
// S[10][256]: 0=ctx partial (mt0..2), 1=ctx partial (mt3), 2+ch=choice sums.
// Ag[16][264] bf16 agg -> f_phi (1 16x16 tile/wave) -> W4 dot -> out[b*8+ch].
__global__ __launch_bounds__(1024) void k2_kernel(
    const bf16_t* __restrict__ UV, const float* __restrict__ b1,
    const float* __restrict__ b2, const bf16_t* __restrict__ W2T,
    const bf16_t* __restrict__ W3T, const float* __restrict__ b3,
    const float* __restrict__ W4, const float* __restrict__ b4,
    float* __restrict__ out) {
  __shared__ char smem[52224];                        // h1[192][136] bf16
  bf16_t (*h1)[136] = (bf16_t(*)[136])smem;
  float (*S)[256] = (float(*)[256])smem;              // 10240 B (after h1 dead)
  bf16_t (*Ag)[264] = (bf16_t(*)[264])(smem + 10240); // 8448 B
  float (*red)[8] = (float(*)[8])(smem + 10240 + 8448); // 512 B
  const int b = blockIdx.x;
  const int t = threadIdx.x;
  const int lane = t & 63;
  const int w = t >> 6;          // 0..15
  const int col = lane & 15;
  const int quad = lane >> 4;
  // staging role (threads 0..767: 4 per row, 32 cols each per phase)
  const bf16_t* su = nullptr;
  const bf16_t* sv = nullptr;
  int sr = 0, sc0 = 0;
  if (t < 768) {
    sr = t >> 2;                 // 0..191
    sc0 = (t & 3) * 32;
    if (sr < 56) {
      const int i = sr / 7;
      const int jj = sr - i * 7;
      const int j = jj + (jj >= i ? 1 : 0);
      su = UV + (size_t)(b * 16 + i) * 512;
      sv = UV + (size_t)(b * 16 + j) * 512 + 256;
    } else if (sr >= 64) {
      const int ch = (sr - 64) >> 4;
      const int rr = (sr - 64) & 15;
      if (rr < 8) {
        su = UV + (size_t)(b * 16 + 8 + ch) * 512;
        sv = UV + (size_t)(b * 16 + rr) * 512 + 256;
      } else {
        su = UV + (size_t)(b * 16 + (rr - 8)) * 512;
        sv = UV + (size_t)(b * 16 + 8 + ch) * 512 + 256;
      }
    }
  }
  const int g = w & 3;           // mt group: tiles 3g..3g+2
  const int q = w >> 2;          // nt quarter
  f32x4 acc[3][4] = {};
  for (int half = 0; half < 2; ++half) {
    const int kbase = half * 128;
    if (t < 768) {
      if (su) {
        for (int c = sc0; c < sc0 + 32; c += 8) {
          const bf16x8 u8 = *(const bf16x8*)(su + kbase + c);
          const bf16x8 v8 = *(const bf16x8*)(sv + kbase + c);
          const f32x4 bb0 = *(const f32x4*)(b1 + kbase + c);
          const f32x4 bb1 = *(const f32x4*)(b1 + kbase + c + 4);
          bf16x8 y;
          for (int e = 0; e < 4; ++e)
            y[e] = (bf16_t)fmaxf((float)u8[e] + (float)v8[e] + bb0[e], 0.0f);
          for (int e = 0; e < 4; ++e)
            y[4 + e] = (bf16_t)fmaxf((float)u8[4 + e] + (float)v8[4 + e] + bb1[e], 0.0f);
          *(bf16x8*)(&h1[sr][c]) = y;
        }
      } else if (half == 0) {    // zero-pad rows 56..63 once; phase 1 skips them
        for (int c = sc0; c < sc0 + 32; c += 8)
          *(bf16x8*)(&h1[sr][c]) = (bf16x8)0.0f;
      }
    }
    __syncthreads();
    for (int ks = 0; ks < 4; ++ks) {
      const int k = ks * 32 + quad * 8;  // within-phase k, <128
      bf16x8 af[3], bf[4];
      for (int mt = 0; mt < 3; ++mt)
        af[mt] = *(const bf16x8*)(&h1[(g * 3 + mt) * 16 + col][k]);
      for (int nt = 0; nt < 4; ++nt) {
        const int n = q * 64 + nt * 16 + col;
        bf[nt] = *(const bf16x8*)(W2T + (size_t)n * 256 + kbase + k);
      }
      for (int mt = 0; mt < 3; ++mt)
        for (int nt = 0; nt < 4; ++nt)
          acc[mt][nt] = MFMA16(af[mt], bf[nt], acc[mt][nt]);
    }
    __syncthreads();   // MFMAs done; h1 dead after half==1 -> S/Ag overlay OK
  }
  // epilogue: tile-column sums of relu(acc + b2) -> S (overlays h1)
  for (int nt = 0; nt < 4; ++nt) {
    const int n = q * 64 + nt * 16 + col;
    const float b2c = b2[n];
    float sctx = 0.0f;
    for (int mt = 0; mt < 3; ++mt) {
      const int gm = g * 3 + mt;           // global 16-row tile 0..11
      float s = 0.0f;
      for (int reg = 0; reg < 4; ++reg) {
        const int row = gm * 16 + quad * 4 + reg;
        if (row < 56 || row >= 64) s += fmaxf(acc[mt][nt][reg] + b2c, 0.0f);
      }
      s += __shfl_xor(s, 16);
      s += __shfl_xor(s, 32);
      if (gm < 3) {
        sctx += s;                         // g==0 waves: tiles 0..2 (ctx)
      } else if (gm == 3) {
        if (lane < 16) S[1][n] = s;        // ctx partial (rows 48..55 + pad)
      } else if (lane < 16) {
        S[2 + (gm - 4)][n] = s;            // choice gm-4
      }
    }
    if (g == 0 && lane < 16) S[0][n] = sctx;
  }
  __syncthreads();
  // Ag rows 0..7 = bf16 agg per choice; rows 8..15 zero (M=16 pad)
  if (t < 512) {
    const int ch = t >> 6;
    const int n0 = (t & 63) * 4;
    bf16x4 y;
    for (int e = 0; e < 4; ++e)
      y[e] = (bf16_t)((S[0][n0 + e] + S[1][n0 + e] + S[2 + ch][n0 + e]) * (1.0f / 72.0f));
    *(bf16x4*)(&Ag[ch][n0]) = y;
    *(bf16x4*)(&Ag[8 + ch][n0]) = (bf16x4)0.0f;
  }
  __syncthreads();
  // f_phi: g = relu(Ag@W3+b3); score = g@W4 + b4. wave w -> n in [w*16,+16).
  f32x4 acc2 = {};
  {
    const int n = w * 16 + col;
    for (int ks = 0; ks < 8; ++ks) {
      const int k = ks * 32 + quad * 8;
      const bf16x8 af = *(const bf16x8*)(&Ag[col][k]);
      const bf16x8 bf = *(const bf16x8*)(W3T + (size_t)n * 256 + k);
      acc2 = MFMA16(af, bf, acc2);
    }
  }
  {
    const int n = w * 16 + col;
    const float b3c = b3[n];
    const float w4c = W4[n];
    for (int reg = 0; reg < 4; ++reg) {
      float pr = fmaxf(acc2[reg] + b3c, 0.0f) * w4c;
      pr += __shfl_xor(pr, 1);
      pr += __shfl_xor(pr, 2);
      pr += __shfl_xor(pr, 4);
      pr += __shfl_xor(pr, 8);
      if (col == 0 && quad < 2) red[w][quad * 4 + reg] = pr;  // rows 8..15 dropped
    }
  }
  __syncthreads();
  if (t < 8) {
    float sc = b4[0];
    for (int ww = 0; ww < 16; ++ww) sc += red[ww][t];
    out[b * 8 + t] = sc;
  }
}

extern "C" void kernel_launch(void* const* d_in, const int* in_sizes, int n_in,
                              void* d_out, int out_size, void* d_ws, size_t ws_size,
                              hipStream_t stream) {
  (void)in_sizes; (void)n_in; (void)out_size; (void)ws_size;
  const float* ctx = (const float*)d_in[0];
  const float* cho = (const float*)d_in[1];
  const float* W1  = (const float*)d_in[2];
  const float* b1  = (const float*)d_in[3];
  const float* W2  = (const float*)d_in[4];
  const float* b2  = (const float*)d_in[5];
  const float* W3  = (const float*)d_in[6];
  const float* b3  = (const float*)d_in[7];
  const float* W4  = (const float*)d_in[8];
  const float* b4  = (const float*)d_in[9];
  char* ws = (char*)d_ws;
  bf16_t* Wp   = (bf16_t*)(ws + 0);
  bf16_t* W2T  = (bf16_t*)(ws + 524288);
  bf16_t* W3T  = (bf16_t*)(ws + 655360);
  bf16_t* UV   = (bf16_t*)(ws + 786432);
  float*  out  = (float*)d_out;

  prep_kernel<<<dim3(96), dim3(256), 0, stream>>>(W1, W2, W3, Wp, W2T, W3T);
  k1_kernel<<<dim3(256), dim3(512), 0, stream>>>(ctx, cho, Wp, UV);
  k2_kernel<<<dim3(256), dim3(1024), 0, stream>>>(UV, b1, b2, W2T, W3T, b3, W4, b4, out);
}

// Round 11
// 110.363 us; speedup vs baseline: 1.0563x; 1.0563x over previous
//
#include <hip/hip_runtime.h>
#include <hip/hip_bf16.h>

// RelationNetwork fused pipeline, bf16 MFMA (gfx950).
//
// Factorizations:
//  (1) pair@W1 = u[i]+v[j]  -> one 4096x512x512 GEMM (K1).
//  (2) ctx-ctx pair sum is choice-invariant -> computed once per b inside K2.
//  (3) f_phi fused into K2 (no K3, no agg round-trip).
//  (4) K1 stages fp32 X into a shared LDS bf16 A-tile.
//  (5) UV stored bf16.
//  (6) prep via LDS 64x64 tile transpose; K1 256 blocks x 512 thr.
//  (7) K2 512 thr / 8 waves (r9's 1024-thr regressed: 2x W2T redundancy).
//  (8) r11: NO LDS aliasing. r10 hit a post-timing divergence on code
//      byte-identical to r8's pass -> latent nondeterminism; the only
//      unverifiable construct was the S/Ag/red overlay of dead h1. Ag is
//      eliminated (f_phi builds A-frags straight from S, same rounding
//      point), so h1 + S + red fit in 64 KB as disjoint arrays.
//
// ws layout (bytes):
//   [0,        524288)   Wp   bf16 [512][512]  Wp[j][k]=W1'[k][j]
//   [524288,   655360)   W2T  bf16 [256][256]
//   [655360,   786432)   W3T  bf16 [256][256]
//   [786432,   4980736)  UV   bf16 [4096][512] row b*16+p; cols 0..255=u, 256..511=v

typedef __bf16 bf16_t;
typedef bf16_t bf16x8 __attribute__((ext_vector_type(8)));
typedef bf16_t bf16x4 __attribute__((ext_vector_type(4)));
typedef float f32x4 __attribute__((ext_vector_type(4)));

#define MFMA16(a, b, c) __builtin_amdgcn_mfma_f32_16x16x32_bf16((a), (b), (c), 0, 0, 0)

// ---- K0: weight transposes via LDS tiles (96 blocks x 256 thr) -------------
__global__ __launch_bounds__(256) void prep_kernel(
    const float* __restrict__ W1, const float* __restrict__ W2,
    const float* __restrict__ W3, bf16_t* __restrict__ Wp,
    bf16_t* __restrict__ W2T, bf16_t* __restrict__ W3T) {
  __shared__ float Ts[64][65];
  const int b = blockIdx.x;
  const int t = threadIdx.x;
  const int r = t >> 6;          // 0..3
  const int c = t & 63;
  const float* srcP;
  bf16_t* dstP;
  int srcRow, srcCol, dr0, dc0, dstride;
  if (b < 64) {                  // Wp tile: tk = b>>3, tj = b&7
    const int k0 = (b >> 3) * 64, j0 = (b & 7) * 64;
    srcP = W1; dstP = Wp; dstride = 512;
    srcRow = (j0 < 256) ? k0 : 512 + k0;
    srcCol = (j0 < 256) ? j0 : j0 - 256;
    dr0 = j0; dc0 = k0;
  } else if (b < 80) {           // W2T tile
    const int s = b - 64;
    const int k0 = (s >> 2) * 64, n0 = (s & 3) * 64;
    srcP = W2; dstP = W2T; dstride = 256;
    srcRow = k0; srcCol = n0; dr0 = n0; dc0 = k0;
  } else {                       // W3T tile
    const int s = b - 80;
    const int k0 = (s >> 2) * 64, n0 = (s & 3) * 64;
    srcP = W3; dstP = W3T; dstride = 256;
    srcRow = k0; srcCol = n0; dr0 = n0; dc0 = k0;
  }
  for (int i = 0; i < 16; ++i) {           // 16 iters x 4 rows = 64 rows
    const int a = i * 4 + r;
    Ts[a][c] = srcP[(size_t)(srcRow + a) * 256 + srcCol + c];
  }
  __syncthreads();
  for (int i = 0; i < 16; ++i) {
    const int j = i * 4 + r;
    dstP[(size_t)(dr0 + j) * dstride + dc0 + c] = (bf16_t)Ts[c][j];
  }
}

// ---- K1: UV = X @ Wp^T  (M=4096, N=512, K=512), bf16 output ----------------
// 256 blocks = 64 Mtiles(64) x 4 Ntiles(128); 512 thr = 8 waves (4mt x 1nt).
__global__ __launch_bounds__(512) void k1_kernel(
    const float* __restrict__ ctx, const float* __restrict__ cho,
    const bf16_t* __restrict__ Wp, bf16_t* __restrict__ UV) {
  __shared__ bf16_t As[64][264];           // 33.8 KB; row bank-stride 4 -> 2-way max
  const int bm = blockIdx.x & 63;
  const int bn = blockIdx.x >> 6;          // 0..3
  const int t = threadIdx.x;
  const int lane = t & 63;
  const int w = t >> 6;                    // 0..7
  const int col = lane & 15;
  const int quad = lane >> 4;
  const int n = bn * 128 + w * 16 + col;
  const int sr = t >> 3;                   // staging: 8 threads/row
  const int gr = bm * 64 + sr;             // X row = b*16 + p
  const int bi = gr >> 4;
  const int p = gr & 15;
  const float* src = (p < 8) ? ctx + (size_t)(bi * 8 + p) * 512
                             : cho + (size_t)(bi * 8 + (p - 8)) * 512;
  const int cb = (t & 7) * 4;
  f32x4 acc[4] = {};
  for (int half = 0; half < 2; ++half) {
    const int kbase = half * 256;
    for (int i = 0; i < 8; ++i) {
      const int c = cb + i * 32;
      const f32x4 x = *(const f32x4*)(src + kbase + c);
      bf16x4 y;
      for (int e = 0; e < 4; ++e) y[e] = (bf16_t)x[e];
      *(bf16x4*)(&As[sr][c]) = y;
    }
    __syncthreads();
    for (int ks = 0; ks < 8; ++ks) {
      const int k = ks * 32 + quad * 8;
      bf16x8 af[4];
      for (int mt = 0; mt < 4; ++mt)
        af[mt] = *(const bf16x8*)(&As[mt * 16 + col][k]);
      const bf16x8 bf = *(const bf16x8*)(Wp + (size_t)n * 512 + kbase + k);
      for (int mt = 0; mt < 4; ++mt) acc[mt] = MFMA16(af[mt], bf, acc[mt]);
    }
    __syncthreads();
  }
  for (int mt = 0; mt < 4; ++mt)
    for (int reg = 0; reg < 4; ++reg) {
      const int r = bm * 64 + mt * 16 + quad * 4 + reg;
      UV[(size_t)r * 512 + n] = (bf16_t)acc[mt][reg];
    }
}

// ---- K2: merged relation stage + f_phi. One block per b (256 blk, 512 thr).
// Rows r in [0,192): r<56 ctx pair; 56..63 zero pad; r=64+ch*16+rr choice pair.
// h1 staged in LDS in two K=128 phases. 8 waves: w&1 -> mt half (6 tiles),
// w>>1 -> nt quarter. Epilogue: column sums -> S[9][260] (S[0]=ctx, S[1+ch]);
// f_phi A-frags built per-lane from S (row=col choice, bf16 round identical
// to the old Ag path), B=W3T, W4 dot -> out[b*8+ch]. NO LDS aliasing.
__global__ __launch_bounds__(512) void k2_kernel(
    const bf16_t* __restrict__ UV, const float* __restrict__ b1,
    const float* __restrict__ b2, const bf16_t* __restrict__ W2T,
    const bf16_t* __restrict__ W3T, const float* __restrict__ b3,
    const float* __restrict__ W4, const float* __restrict__ b4,
    float* __restrict__ out) {
  __shared__ bf16_t h1[192][136];   // 52224 B
  __shared__ float S[9][260];       // 9360 B (stride 260: 16B rows, 4-bank col step)
  __shared__ float red[8][8];       // 256 B   -> total 61840 B, all disjoint
  const int b = blockIdx.x;
  const int t = threadIdx.x;
  const int lane = t & 63;
  const int w = t >> 6;
  const int col = lane & 15;
  const int quad = lane >> 4;
  // staging role (threads 0..383: 2 per row)
  const bf16_t* su = nullptr;
  const bf16_t* sv = nullptr;
  int sr = 0, sc0 = 0;
  if (t < 384) {
    sr = t >> 1;
    sc0 = (t & 1) * 64;
    if (sr < 56) {
      const int i = sr / 7;
      const int jj = sr - i * 7;
      const int j = jj + (jj >= i ? 1 : 0);
      su = UV + (size_t)(b * 16 + i) * 512;
      sv = UV + (size_t)(b * 16 + j) * 512 + 256;
    } else if (sr >= 64) {
      const int ch = (sr - 64) >> 4;
      const int rr = (sr - 64) & 15;
      if (rr < 8) {
        su = UV + (size_t)(b * 16 + 8 + ch) * 512;
        sv = UV + (size_t)(b * 16 + rr) * 512 + 256;
      } else {
        su = UV + (size_t)(b * 16 + (rr - 8)) * 512;
        sv = UV + (size_t)(b * 16 + 8 + ch) * 512 + 256;
      }
    }
  }
  const int mtb = (w & 1) * 6;   // mt base (6 tiles)
  const int q = w >> 1;          // nt quarter
  f32x4 acc[6][4] = {};
  for (int half = 0; half < 2; ++half) {
    const int kbase = half * 128;
    if (t < 384) {
      if (su) {
        for (int c = sc0; c < sc0 + 64; c += 8) {
          const bf16x8 u8 = *(const bf16x8*)(su + kbase + c);
          const bf16x8 v8 = *(const bf16x8*)(sv + kbase + c);
          const f32x4 bb0 = *(const f32x4*)(b1 + kbase + c);
          const f32x4 bb1 = *(const f32x4*)(b1 + kbase + c + 4);
          bf16x8 y;
          for (int e = 0; e < 4; ++e)
            y[e] = (bf16_t)fmaxf((float)u8[e] + (float)v8[e] + bb0[e], 0.0f);
          for (int e = 0; e < 4; ++e)
            y[4 + e] = (bf16_t)fmaxf((float)u8[4 + e] + (float)v8[4 + e] + bb1[e], 0.0f);
          *(bf16x8*)(&h1[sr][c]) = y;
        }
      } else if (half == 0) {    // zero-pad rows 56..63 once; nothing overwrites
        for (int c = sc0; c < sc0 + 64; c += 8)
          *(bf16x8*)(&h1[sr][c]) = (bf16x8)0.0f;
      }
    }
    __syncthreads();
    for (int ks = 0; ks < 4; ++ks) {
      const int k = ks * 32 + quad * 8;  // within-phase k, <128
      bf16x8 af[6], bf[4];
      for (int mt = 0; mt < 6; ++mt)
        af[mt] = *(const bf16x8*)(&h1[(mtb + mt) * 16 + col][k]);
      for (int nt = 0; nt < 4; ++nt) {
        const int n = q * 64 + nt * 16 + col;
        bf[nt] = *(const bf16x8*)(W2T + (size_t)n * 256 + kbase + k);
      }
      for (int mt = 0; mt < 6; ++mt)
        for (int nt = 0; nt < 4; ++nt)
          acc[mt][nt] = MFMA16(af[mt], bf[nt], acc[mt][nt]);
    }
    __syncthreads();
  }
  // epilogue: tile-column sums of relu(acc + b2) -> S
  for (int nt = 0; nt < 4; ++nt) {
    const int n = q * 64 + nt * 16 + col;
    const float b2c = b2[n];
    float sctx = 0.0f;
    for (int mt = 0; mt < 6; ++mt) {
      const int gm = mtb + mt;
      float s = 0.0f;
      for (int reg = 0; reg < 4; ++reg) {
        const int row = gm * 16 + quad * 4 + reg;
        if (row < 56 || row >= 64) s += fmaxf(acc[mt][nt][reg] + b2c, 0.0f);
      }
      s += __shfl_xor(s, 16);
      s += __shfl_xor(s, 32);
      if (gm < 4) {
        sctx += s;                       // only waves with mtb==0
      } else if (lane < 16) {
        S[1 + (gm - 4)][n] = s;
      }
    }
    if (mtb == 0 && lane < 16) S[0][n] = sctx;
  }
  __syncthreads();
  // f_phi: g = relu(A@W3+b3); score = g@W4 + b4. wave w -> n in [w*32,+32).
  // A row m=col: (S[0]+S[1+col])/72 rounded to bf16 (same as old Ag path);
  // rows 8..15 zero.
  f32x4 acc2[2] = {};
  for (int ks = 0; ks < 8; ++ks) {
    const int k = ks * 32 + quad * 8;
    bf16x8 af;
    if (col < 8) {
      const f32x4 s0a = *(const f32x4*)(&S[0][k]);
      const f32x4 s0b = *(const f32x4*)(&S[0][k + 4]);
      const f32x4 s1a = *(const f32x4*)(&S[1 + col][k]);
      const f32x4 s1b = *(const f32x4*)(&S[1 + col][k + 4]);
      for (int e = 0; e < 4; ++e)
        af[e] = (bf16_t)((s0a[e] + s1a[e]) * (1.0f / 72.0f));
      for (int e = 0; e < 4; ++e)
        af[4 + e] = (bf16_t)((s0b[e] + s1b[e]) * (1.0f / 72.0f));
    } else {
      af = (bf16x8)0.0f;
    }
    for (int nt = 0; nt < 2; ++nt) {
      const int n = w * 32 + nt * 16 + col;
      const bf16x8 bf = *(const bf16x8*)(W3T + (size_t)n * 256 + k);
      acc2[nt] = MFMA16(af, bf, acc2[nt]);
    }
  }
  for (int reg = 0; reg < 4; ++reg) {
    float pr = 0.0f;
    for (int nt = 0; nt < 2; ++nt) {
      const int n = w * 32 + nt * 16 + col;
      pr += fmaxf(acc2[nt][reg] + b3[n], 0.0f) * W4[n];
    }
    pr += __shfl_xor(pr, 1);
    pr += __shfl_xor(pr, 2);
    pr += __shfl_xor(pr, 4);
    pr += __shfl_xor(pr, 8);
    if (col == 0 && quad < 2) red[w][quad * 4 + reg] = pr;  // C rows 8..15 dropped
  }
  __syncthreads();
  if (t < 8) {
    float sc = b4[0];
    for (int ww = 0; ww < 8; ++ww) sc += red[ww][t];
    out[b * 8 + t] = sc;
  }
}

extern "C" void kernel_launch(void* const* d_in, const int* in_sizes, int n_in,
                              void* d_out, int out_size, void* d_ws, size_t ws_size,
                              hipStream_t stream) {
  (void)in_sizes; (void)n_in; (void)out_size; (void)ws_size;
  const float* ctx = (const float*)d_in[0];
  const float* cho = (const float*)d_in[1];
  const float* W1  = (const float*)d_in[2];
  const float* b1  = (const float*)d_in[3];
  const float* W2  = (const float*)d_in[4];
  const float* b2  = (const float*)d_in[5];
  const float* W3  = (const float*)d_in[6];
  const float* b3  = (const float*)d_in[7];
  const float* W4  = (const float*)d_in[8];
  const float* b4  = (const float*)d_in[9];
  char* ws = (char*)d_ws;
  bf16_t* Wp   = (bf16_t*)(ws + 0);
  bf16_t* W2T  = (bf16_t*)(ws + 524288);
  bf16_t* W3T  = (bf16_t*)(ws + 655360);
  bf16_t* UV   = (bf16_t*)(ws + 786432);
  float*  out  = (float*)d_out;

  prep_kernel<<<dim3(96), dim3(256), 0, stream>>>(W1, W2, W3, Wp, W2T, W3T);
  k1_kernel<<<dim3(256), dim3(512), 0, stream>>>(ctx, cho, Wp, UV);
  k2_kernel<<<dim3(256), dim3(512), 0, stream>>>(UV, b1, b2, W2T, W3T, b3, W4, b4, out);
}